// Round 6
// baseline (554.882 us; speedup 1.0000x reference)
//
#include <hip/hip_runtime.h>

typedef __attribute__((ext_vector_type(8))) short short8;
typedef __attribute__((ext_vector_type(4))) float floatx4;

__device__ __forceinline__ unsigned short f2bf(float f) {
  union { float f; unsigned int u; } x; x.f = f;
  unsigned int r = (x.u + 0x7fffu + ((x.u >> 16) & 1u)) >> 16;
  return (unsigned short)r;
}
__device__ __forceinline__ float bf2f(unsigned short u) {
  union { unsigned int u; float f; } x; x.u = ((unsigned int)u) << 16;
  return x.f;
}

__device__ __forceinline__ void gload_lds16(const void* g, void* l) {
  __builtin_amdgcn_global_load_lds((const __attribute__((address_space(1))) void*)g,
                                   (__attribute__((address_space(3))) void*)l,
                                   16, 0, 0);
}

// ---------------------------------------------------------------------------
// Merged prep + cast (one dispatch). Blocks [0,16384): cast x fp32 -> xb bf16
// (128 thr x 2 float4). Blocks [16384,17408): densify masked weights into
// Wqkv [3072][1024] bf16 (rows 0-1023 = (Wl*mask)@(Wq*mask), 1024+ = Wk*mask,
// 2048+ = Wv*mask) and biasAll[3072] = [ (Wl*mask)@bq | bk | bv ].
// ---------------------------------------------------------------------------
__global__ __launch_bounds__(128) void prep_cast(
    const float* __restrict__ Wq, const float* __restrict__ Wk,
    const float* __restrict__ Wv, const float* __restrict__ Wl,
    const float* __restrict__ bq, const float* __restrict__ bk,
    const float* __restrict__ bv,
    unsigned short* __restrict__ Wqkv, float* __restrict__ biasAll,
    const float4* __restrict__ x, ushort4* __restrict__ xb) {
  const int t = threadIdx.x;
  if (blockIdx.x < 16384) {
    int i = blockIdx.x * 256 + t;
#pragma unroll
    for (int k = 0; k < 2; ++k) {
      float4 v = x[i + k * 128];
      ushort4 o;
      o.x = f2bf(v.x); o.y = f2bf(v.y); o.z = f2bf(v.z); o.w = f2bf(v.w);
      xb[i + k * 128] = o;
    }
    return;
  }
  const int i = blockIdx.x - 16384;
  const int r = i >> 5, c = i & 31;
  {
    short8 z = (short8){0, 0, 0, 0, 0, 0, 0, 0};
    ((short8*)Wqkv)[i * 128 + t] = z;
    ((short8*)Wqkv)[(1024 + i) * 128 + t] = z;
    ((short8*)Wqkv)[(2048 + i) * 128 + t] = z;
  }
  __syncthreads();
  if (t < 25) {
    int dr = t / 5 - 2, dc = t % 5 - 2;
    int j = (((r + dr) & 31) << 5) | ((c + dc) & 31);
    Wqkv[(1024 + i) * 1024 + j] = f2bf(Wk[i * 1024 + j]);
    Wqkv[(2048 + i) * 1024 + j] = f2bf(Wv[i * 1024 + j]);
  }
  if (t < 81) {
    int dr = t / 9 - 4, dc = t % 9 - 4;
    int j = (((r + dr) & 31) << 5) | ((c + dc) & 31);
    float s = 0.f;
    int erlo = dr - 2 < -2 ? -2 : dr - 2, erhi = dr + 2 > 2 ? 2 : dr + 2;
    int eclo = dc - 2 < -2 ? -2 : dc - 2, echi = dc + 2 > 2 ? 2 : dc + 2;
    for (int er = erlo; er <= erhi; ++er)
      for (int ec = eclo; ec <= echi; ++ec) {
        int m = (((r + er) & 31) << 5) | ((c + ec) & 31);
        s += Wl[i * 1024 + m] * Wq[m * 1024 + j];
      }
    Wqkv[i * 1024 + j] = f2bf(s);
  }
  if (t == 96) {
    float s = 0.f;
    for (int e = 0; e < 25; ++e) {
      int dr = e / 5 - 2, dc = e % 5 - 2;
      int m = (((r + dr) & 31) << 5) | ((c + dc) & 31);
      s += Wl[i * 1024 + m] * bq[m];
    }
    biasAll[i] = s;
  }
  if (t == 97) biasAll[1024 + i] = bk[i];
  if (t == 98) biasAll[2048 + i] = bv[i];
}

// ---------------------------------------------------------------------------
// 256x256-tile, BK=64, 8-wave (2Mx4N) GEMM, m201 cadence (8 phases / 2
// K-tiles, one half-tile staged per slot, counted vmcnt(4)/(6), never 0
// mid-loop), XOR swizzle (g ^ (row&7)) on stage-source and ds_read,
// bijective XCD-aware block swizzle (flat grid, bn fastest).
// OUTMODE 0: QKV. bn<8: bf16 q/k out + bias; bn>=8: bias-added V written
//   transposed to vT[b][h][s] via LDS tile (fused transpose).
// OUTMODE 2: e=exp(acc*scale) bf16 out + row partials -> Lpart[row*8+bn]
// OUTMODE 3: PV with FUSED softmax finish: prologue computes invL[256 rows]
//   from Lpart into LDS; main loop writes probs = e*invL fp32 for this
//   block's col-quarter (tiles T in [bn*8,bn*8+8)) straight from the staged
//   A-LDS tiles; epilogue writes out = acc*invL. (probs stores inflate the
//   counted vmcnt only conservatively: stores are newest, so draining to <=N
//   retires at least the same staging loads.)
// ---------------------------------------------------------------------------
template <int OUTMODE>
__global__ __launch_bounds__(512, 2) void gemm256(
    const unsigned short* __restrict__ A, const unsigned short* __restrict__ B,
    void* __restrict__ Cv, const float* __restrict__ auxc, float* __restrict__ auxw,
    int lda, int ldb, int ldc, int K, float scale,
    size_t sA, size_t sB, size_t sC, int nx, int ny) {
  // K-loop staging: bytes [0,131072). invL (OUTMODE 3): floats at byte 131072.
  // OUTMODE 0 v-epilogue reuses as [256][264] ushort tile (132 KiB).
  __shared__ __align__(16) unsigned short lds[67584];
  const int t = threadIdx.x;
  const int lane = t & 63;
  const int wv = t >> 6;          // 0..7
  const int wm = wv >> 2;         // 0..1  (row half)
  const int wn = wv & 3;          // 0..3  (col quarter)
  const int l15 = lane & 15, lq = lane >> 4;

  // --- XCD-aware bijective swizzle (nwg % 8 == 0 guaranteed by launches) ---
  const int nwg = gridDim.x;
  const int hid = blockIdx.x;
  const int logical = (hid & 7) * (nwg >> 3) + (hid >> 3);
  const int bn = logical % nx;
  const int bm = (logical / nx) % ny;
  const int bz = logical / (nx * ny);

  A += sA * bz; B += sB * bz;

  const int srow = t >> 3;               // staging row within half 0..63
  const int sg = (t & 7) ^ (srow & 7);   // pre-swizzled 16B-group in source

  float* lds_invL = (float*)&lds[65536];
  float* probs_base = (OUTMODE == 3) ? (auxw + (size_t)bz * 4194304) : nullptr;
  float il_h0 = 0.f, il_h1 = 0.f;

  if (OUTMODE == 3) {
    // invL prologue: 1/sum of 8 partials per row, into LDS (and drain fully
    // so the staging vmcnt ledger starts at 0 outstanding).
    if (t < 256) {
      const float4* Lp = (const float4*)&auxc[((size_t)bz * 2048 + bm * 256 + t) * 8];
      float4 a = Lp[0], b = Lp[1];
      float s = a.x + a.y + a.z + a.w + b.x + b.y + b.z + b.w;
      lds_invL[t] = 1.0f / s;
    }
    asm volatile("s_waitcnt vmcnt(0) lgkmcnt(0)" ::: "memory");
    __builtin_amdgcn_s_barrier();
    il_h0 = lds_invL[t >> 2];
    il_h1 = lds_invL[128 + (t >> 2)];
  }

  // Stage one half-tile (128 rows x 64 cols): 2 gload_lds x 512 thr x 16B.
#define STG_A(h, tile_) do {                                                     \
    gload_lds16(A + (size_t)(bm * 256 + (h) * 128 + srow) * lda + (tile_) * 64 + sg * 8, \
                &lds[(((tile_) & 1) << 14) + (h) * 8192 + wv * 512]);            \
    gload_lds16(A + (size_t)(bm * 256 + (h) * 128 + 64 + srow) * lda + (tile_) * 64 + sg * 8, \
                &lds[(((tile_) & 1) << 14) + (h) * 8192 + 4096 + wv * 512]);     \
  } while (0)
#define STG_B(h, tile_) do {                                                     \
    gload_lds16(B + (size_t)(bn * 256 + (h) * 128 + srow) * ldb + (tile_) * 64 + sg * 8, \
                &lds[32768 + (((tile_) & 1) << 14) + (h) * 8192 + wv * 512]);    \
    gload_lds16(B + (size_t)(bn * 256 + (h) * 128 + 64 + srow) * ldb + (tile_) * 64 + sg * 8, \
                &lds[32768 + (((tile_) & 1) << 14) + (h) * 8192 + 4096 + wv * 512]); \
  } while (0)

#define LOADA(arr, ro)                                                           \
  _Pragma("unroll") for (int i = 0; i < 4; ++i) {                                \
    int rA = wm * 128 + (ro) + i * 16 + l15;                                     \
    _Pragma("unroll") for (int ks = 0; ks < 2; ++ks)                             \
      arr[i][ks] = *(const short8*)&lds[bo_ + rA * 64 + (((ks * 4 + lq) ^ (rA & 7)) << 3)]; \
  }
#define LOADB(arr, ro)                                                           \
  _Pragma("unroll") for (int j = 0; j < 2; ++j) {                                \
    int rB = wn * 64 + (ro) + j * 16 + l15;                                      \
    _Pragma("unroll") for (int ks = 0; ks < 2; ++ks)                             \
      arr[j][ks] = *(const short8*)&lds[32768 + bo_ + rB * 64 + (((ks * 4 + lq) ^ (rB & 7)) << 3)]; \
  }
#define MFMA8(mb, nb, aa, bb)                                                    \
  _Pragma("unroll") for (int i = 0; i < 4; ++i)                                  \
    _Pragma("unroll") for (int j = 0; j < 2; ++j) {                              \
      acc[(mb) + i][(nb) + j] = __builtin_amdgcn_mfma_f32_16x16x32_bf16(         \
          aa[i][0], bb[j][0], acc[(mb) + i][(nb) + j], 0, 0, 0);                 \
      acc[(mb) + i][(nb) + j] = __builtin_amdgcn_mfma_f32_16x16x32_bf16(         \
          aa[i][1], bb[j][1], acc[(mb) + i][(nb) + j], 0, 0, 0);                 \
    }
  // probs = e * invL for 16 cols of row (hb + t>>2) of the staged A tile.
#define PWRITE(bo_, T_, hb, il) do {                                             \
    int pr = (hb) + (t >> 2);                                                    \
    int g0 = (t & 3) * 2;                                                        \
    short8 e0 = *(const short8*)&lds[(bo_) + pr * 64 + (((g0 ^ (pr & 7))) << 3)];\
    short8 e1 = *(const short8*)&lds[(bo_) + pr * 64 + ((((g0 + 1) ^ (pr & 7))) << 3)]; \
    float* dst = probs_base + (size_t)(bm * 256 + pr) * 2048 + (T_) * 64 + (t & 3) * 16; \
    float4 w;                                                                    \
    w.x = bf2f((unsigned short)e0[0]) * (il); w.y = bf2f((unsigned short)e0[1]) * (il); \
    w.z = bf2f((unsigned short)e0[2]) * (il); w.w = bf2f((unsigned short)e0[3]) * (il); \
    *(float4*)&dst[0] = w;                                                       \
    w.x = bf2f((unsigned short)e0[4]) * (il); w.y = bf2f((unsigned short)e0[5]) * (il); \
    w.z = bf2f((unsigned short)e0[6]) * (il); w.w = bf2f((unsigned short)e0[7]) * (il); \
    *(float4*)&dst[4] = w;                                                       \
    w.x = bf2f((unsigned short)e1[0]) * (il); w.y = bf2f((unsigned short)e1[1]) * (il); \
    w.z = bf2f((unsigned short)e1[2]) * (il); w.w = bf2f((unsigned short)e1[3]) * (il); \
    *(float4*)&dst[8] = w;                                                       \
    w.x = bf2f((unsigned short)e1[4]) * (il); w.y = bf2f((unsigned short)e1[5]) * (il); \
    w.z = bf2f((unsigned short)e1[6]) * (il); w.w = bf2f((unsigned short)e1[7]) * (il); \
    *(float4*)&dst[12] = w;                                                      \
  } while (0)
#define FENCE asm volatile("" ::: "memory")
#define BAR __builtin_amdgcn_s_barrier()
#define SP1 __builtin_amdgcn_s_setprio(1)
#define SP0 __builtin_amdgcn_s_setprio(0)

  floatx4 acc[8][4];
#pragma unroll
  for (int i = 0; i < 8; ++i)
#pragma unroll
    for (int j = 0; j < 4; ++j) acc[i][j] = (floatx4){0.f, 0.f, 0.f, 0.f};

  const int NT = K >> 6;  // even, >= 2 (16 or 32 here)

  // Prologue: tile0 fully (8 loads) + B0,A0,B1 of tile1 (6 loads);
  // vmcnt(6) -> tile0 resident, 3 half-tiles of tile1 in flight.
  STG_A(0, 0); STG_A(1, 0); STG_B(0, 0); STG_B(1, 0);
  FENCE;
  STG_B(0, 1); STG_A(0, 1); STG_B(1, 1);
  asm volatile("s_waitcnt vmcnt(6)" ::: "memory");
  BAR;

  for (int T = 0; T < NT; T += 2) {
    short8 aF[4][2], bFa[2][2], bFb[2][2];
    const bool pw0 = (OUTMODE == 3) && (T >= bn * 8) && (T < bn * 8 + 8);
    const bool pw1 = (OUTMODE == 3) && (T + 1 >= bn * 8) && (T + 1 < bn * 8 + 8);
    // ================= tile T (buffer 0) =================
    {
      const int bo_ = 0;
      // ph1: Q(0,0)
      LOADA(aF, 0); LOADB(bFa, 0);
      STG_A(1, T + 1);
      if (pw0) PWRITE(bo_, T, 0, il_h0);
      FENCE; BAR;
      SP1; MFMA8(0, 0, aF, bFa); SP0;
      FENCE; BAR;
      // ph2: Q(0,1)
      LOADB(bFb, 32);
      FENCE; BAR;
      SP1; MFMA8(0, 2, aF, bFb); SP0;
      FENCE; BAR;
      // ph3: Q(1,1)  (reuse aF regs for upper A half)
      LOADA(aF, 64);
      if (T + 2 < NT) STG_B(0, T + 2);
      if (pw0) PWRITE(bo_, T, 128, il_h1);
      FENCE; BAR;
      SP1; MFMA8(4, 2, aF, bFb); SP0;
      FENCE; BAR;
      // ph4: Q(1,0)
      if (T + 2 < NT) STG_A(0, T + 2);
      FENCE; BAR;
      SP1; MFMA8(4, 0, aF, bFa); SP0;
      if (T + 2 < NT) { asm volatile("s_waitcnt vmcnt(4)" ::: "memory"); }
      else            { asm volatile("s_waitcnt vmcnt(0)" ::: "memory"); }
      FENCE; BAR;
    }
    // ================= tile T+1 (buffer 1) =================
    {
      const int bo_ = 1 << 14;
      // ph5: Q(0,0)
      LOADA(aF, 0); LOADB(bFa, 0);
      if (T + 2 < NT) { STG_B(1, T + 2); STG_A(1, T + 2); }
      if (pw1) PWRITE(bo_, T + 1, 0, il_h0);
      FENCE; BAR;
      SP1; MFMA8(0, 0, aF, bFa); SP0;
      FENCE; BAR;
      // ph6: Q(0,1)
      LOADB(bFb, 32);
      FENCE; BAR;
      SP1; MFMA8(0, 2, aF, bFb); SP0;
      FENCE; BAR;
      // ph7: Q(1,1)
      LOADA(aF, 64);
      if (T + 3 < NT) STG_B(0, T + 3);
      if (pw1) PWRITE(bo_, T + 1, 128, il_h1);
      FENCE; BAR;
      SP1; MFMA8(4, 2, aF, bFb); SP0;
      FENCE; BAR;
      // ph8: Q(1,0)
      if (T + 3 < NT) { STG_A(0, T + 3); STG_B(1, T + 3); }
      FENCE; BAR;
      SP1; MFMA8(4, 0, aF, bFa); SP0;
      if (T + 3 < NT) { asm volatile("s_waitcnt vmcnt(6)" ::: "memory"); }
      else            { asm volatile("s_waitcnt vmcnt(0)" ::: "memory"); }
      FENCE; BAR;
    }
  }
#undef STG_A
#undef STG_B
#undef LOADA
#undef LOADB
#undef MFMA8
#undef PWRITE

  // acc[m][n]: row = row0 + (m>>2)*64 + (m&3)*16 + lq*4 + r2
  //            col = col0 + (n>>1)*32 + (n&1)*16 + l15
  const int row0 = bm * 256 + wm * 128;
  const int col0 = bn * 256 + wn * 64;

  if (OUTMODE == 0) {
    if (bn < 8) {
      // q/k blocks: normal bf16 write + bias
      unsigned short* C = (unsigned short*)Cv;
#pragma unroll
      for (int m = 0; m < 8; ++m) {
        int rb = row0 + ((m >> 2) << 6) + ((m & 3) << 4) + (lq << 2);
#pragma unroll
        for (int n = 0; n < 4; ++n) {
          int col = col0 + ((n >> 1) << 5) + ((n & 1) << 4) + l15;
          float bb = auxc[col];
#pragma unroll
          for (int r2 = 0; r2 < 4; ++r2)
            C[(size_t)(rb + r2) * ldc + col] = f2bf(acc[m][n][r2] + bb);
        }
      }
    } else {
      // v blocks: bias + transpose via LDS -> vT[b][h][s] (fused transpose_v)
      unsigned short (*lds2)[264] = (unsigned short (*)[264])lds;
#pragma unroll
      for (int m = 0; m < 8; ++m) {
        int sr = wm * 128 + ((m >> 2) << 6) + ((m & 3) << 4) + (lq << 2);
#pragma unroll
        for (int n = 0; n < 4; ++n) {
          int colg = col0 + ((n >> 1) << 5) + ((n & 1) << 4) + l15;  // 2048..3071
          int h = (colg - 2048) & 255;  // local h within this block's 256 cols
          float bb = auxc[colg];
          ushort4 pk;
          pk.x = f2bf(acc[m][n][0] + bb);
          pk.y = f2bf(acc[m][n][1] + bb);
          pk.z = f2bf(acc[m][n][2] + bb);
          pk.w = f2bf(acc[m][n][3] + bb);
          *(ushort4*)&lds2[h][sr] = pk;  // 8B write, s-contiguous
        }
      }
      __syncthreads();
      unsigned short* vTp = (unsigned short*)auxw;
      const int b = bm >> 3;
      const int s0 = (bm & 7) * 256;
      const int h0 = (bn - 8) * 256;
      const int hh = t >> 1, sh = (t & 1) * 128;
      unsigned short* dst = vTp + ((size_t)b * 1024 + h0 + hh) * 2048 + s0 + sh;
      const unsigned short* src = &lds2[hh][sh];
#pragma unroll
      for (int k2 = 0; k2 < 16; ++k2)
        *(short8*)&dst[k2 * 8] = *(const short8*)&src[k2 * 8];
    }
  } else if (OUTMODE == 2) {
    unsigned short* C = (unsigned short*)Cv + sC * bz;
    float p[8][4];
#pragma unroll
    for (int m = 0; m < 8; ++m)
#pragma unroll
      for (int r2 = 0; r2 < 4; ++r2) p[m][r2] = 0.f;
#pragma unroll
    for (int m = 0; m < 8; ++m) {
      int rb = row0 + ((m >> 2) << 6) + ((m & 3) << 4) + (lq << 2);
#pragma unroll
      for (int n = 0; n < 4; ++n) {
        int col = col0 + ((n >> 1) << 5) + ((n & 1) << 4) + l15;
#pragma unroll
        for (int r2 = 0; r2 < 4; ++r2) {
          float e = __expf(acc[m][n][r2] * scale);
          C[(size_t)(rb + r2) * ldc + col] = f2bf(e);
          p[m][r2] += e;
        }
      }
    }
    // reduce over the 16 lanes (l15) sharing each row
#pragma unroll
    for (int m = 0; m < 8; ++m)
#pragma unroll
      for (int r2 = 0; r2 < 4; ++r2) {
        float v = p[m][r2];
        v += __shfl_xor(v, 1); v += __shfl_xor(v, 2);
        v += __shfl_xor(v, 4); v += __shfl_xor(v, 8);
        p[m][r2] = v;
      }
    float* sred = (float*)lds;  // [4 wn][256 rows]; all LDS traffic drained
    if (l15 == 0) {
#pragma unroll
      for (int m = 0; m < 8; ++m)
#pragma unroll
        for (int r2 = 0; r2 < 4; ++r2)
          sred[wn * 256 + wm * 128 + ((m >> 2) << 6) + ((m & 3) << 4) + (lq << 2) + r2] = p[m][r2];
    }
    __syncthreads();
    if (t < 256) {
      float L = sred[t] + sred[256 + t] + sred[512 + t] + sred[768 + t];
      auxw[((size_t)bz * 2048 + bm * 256 + t) * 8 + bn] = L;
    }
  } else {  // OUTMODE 3: out = acc * invL (invL from LDS)
    float* C = (float*)Cv + sC * bz;
#pragma unroll
    for (int m = 0; m < 8; ++m) {
      int lr = wm * 128 + ((m >> 2) << 6) + ((m & 3) << 4) + (lq << 2);
      float4 il4 = *(const float4*)&lds_invL[lr];
      int rb = row0 + ((m >> 2) << 6) + ((m & 3) << 4) + (lq << 2);
#pragma unroll
      for (int n = 0; n < 4; ++n) {
        int col = col0 + ((n >> 1) << 5) + ((n & 1) << 4) + l15;
        C[(size_t)(rb + 0) * ldc + col] = acc[m][n][0] * il4.x;
        C[(size_t)(rb + 1) * ldc + col] = acc[m][n][1] * il4.y;
        C[(size_t)(rb + 2) * ldc + col] = acc[m][n][2] * il4.z;
        C[(size_t)(rb + 3) * ldc + col] = acc[m][n][3] * il4.w;
      }
    }
  }
}

// ---------------------------------------------------------------------------
extern "C" void kernel_launch(void* const* d_in, const int* in_sizes, int n_in,
                              void* d_out, int out_size, void* d_ws, size_t ws_size,
                              hipStream_t stream) {
  const float* x  = (const float*)d_in[0];
  const float* Wq = (const float*)d_in[1];
  const float* bq = (const float*)d_in[2];
  const float* Wk = (const float*)d_in[3];
  const float* bk = (const float*)d_in[4];
  const float* Wv = (const float*)d_in[5];
  const float* bv = (const float*)d_in[6];
  const float* Wl = (const float*)d_in[7];

  const int B = 8, S = 2048, H = 1024;
  float* out   = (float*)d_out;                     // [B,S,H]
  float* probs = (float*)d_out + (size_t)B * S * H; // [B,S,S]

  char* ws = (char*)d_ws;
  unsigned short* qkv  = (unsigned short*)(ws + 0);           // 100.7MB [16384][3072] (v third unused)
  unsigned short* pb   = (unsigned short*)(ws + 100663296);   // 67MB [B*S][2048] e=exp(s)
  unsigned short* xb   = (unsigned short*)(ws + 167772160);   // 33.5MB
  unsigned short* Wqkv = (unsigned short*)(ws + 201326592);   // 6.3MB [3072][1024]
  float* biasAll       = (float*)(ws + 207618048);            // 12KB
  float* Lpart         = (float*)(ws + 207630336);            // 512KB [16384][8]
  unsigned short* vT   = (unsigned short*)(ws + 209715200);   // 33.5MB [B][H][S]

  prep_cast<<<17408, 128, 0, stream>>>(Wq, Wk, Wv, Wl, bq, bk, bv, Wqkv, biasAll,
                                       (const float4*)x, (ushort4*)xb);

  // qkv(q,k) = x @ Wqkv^T + biasAll; v written transposed to vT (fused)
  gemm256<0><<<768, 512, 0, stream>>>(xb, Wqkv, qkv, biasAll, (float*)vT,
      H, H, 3 * H, H, 1.f, 0, 0, 0, 12, 64);

  // e = exp(q@k^T/32) bf16 -> pb, row-block partial sums -> Lpart (8*8*8)
  gemm256<2><<<512, 512, 0, stream>>>(qkv, qkv + 1024, pb, nullptr, Lpart,
      3 * H, 3 * H, S, H, 1.0f / 32.0f, (size_t)S * 3 * H, (size_t)S * 3 * H, (size_t)S * S, 8, 8);

  // out = (e @ v) * invL ; probs = e * invL written from staged LDS tiles
  gemm256<3><<<256, 512, 0, stream>>>(pb, vT, out, Lpart, probs,
      S, S, H, S, 1.0f, (size_t)S * S, (size_t)H * S, (size_t)S * H, 4, 8);
}

// Round 7
// 523.903 us; speedup vs baseline: 1.0591x; 1.0591x over previous
//
#include <hip/hip_runtime.h>

typedef __attribute__((ext_vector_type(8))) short short8;
typedef __attribute__((ext_vector_type(4))) float floatx4;

__device__ __forceinline__ unsigned short f2bf(float f) {
  union { float f; unsigned int u; } x; x.f = f;
  unsigned int r = (x.u + 0x7fffu + ((x.u >> 16) & 1u)) >> 16;
  return (unsigned short)r;
}
__device__ __forceinline__ float bf2f(unsigned short u) {
  union { unsigned int u; float f; } x; x.u = ((unsigned int)u) << 16;
  return x.f;
}

__device__ __forceinline__ void gload_lds16(const void* g, void* l) {
  __builtin_amdgcn_global_load_lds((const __attribute__((address_space(1))) void*)g,
                                   (__attribute__((address_space(3))) void*)l,
                                   16, 0, 0);
}

// ---------------------------------------------------------------------------
// Merged prep + cast (one dispatch). Blocks [0,16384): cast x fp32 -> xb bf16.
// Blocks [16384,17408): densify masked weights into Wqkv [3072][1024] bf16
// (rows 0-1023 = (Wl*mask)@(Wq*mask), 1024+ = Wk*mask, 2048+ = Wv*mask) and
// biasAll[3072] = [ (Wl*mask)@bq | bk | bv ].
// ---------------------------------------------------------------------------
__global__ __launch_bounds__(128) void prep_cast(
    const float* __restrict__ Wq, const float* __restrict__ Wk,
    const float* __restrict__ Wv, const float* __restrict__ Wl,
    const float* __restrict__ bq, const float* __restrict__ bk,
    const float* __restrict__ bv,
    unsigned short* __restrict__ Wqkv, float* __restrict__ biasAll,
    const float4* __restrict__ x, ushort4* __restrict__ xb) {
  const int t = threadIdx.x;
  if (blockIdx.x < 16384) {
    int i = blockIdx.x * 256 + t;
#pragma unroll
    for (int k = 0; k < 2; ++k) {
      float4 v = x[i + k * 128];
      ushort4 o;
      o.x = f2bf(v.x); o.y = f2bf(v.y); o.z = f2bf(v.z); o.w = f2bf(v.w);
      xb[i + k * 128] = o;
    }
    return;
  }
  const int i = blockIdx.x - 16384;
  const int r = i >> 5, c = i & 31;
  {
    short8 z = (short8){0, 0, 0, 0, 0, 0, 0, 0};
    ((short8*)Wqkv)[i * 128 + t] = z;
    ((short8*)Wqkv)[(1024 + i) * 128 + t] = z;
    ((short8*)Wqkv)[(2048 + i) * 128 + t] = z;
  }
  __syncthreads();
  if (t < 25) {
    int dr = t / 5 - 2, dc = t % 5 - 2;
    int j = (((r + dr) & 31) << 5) | ((c + dc) & 31);
    Wqkv[(1024 + i) * 1024 + j] = f2bf(Wk[i * 1024 + j]);
    Wqkv[(2048 + i) * 1024 + j] = f2bf(Wv[i * 1024 + j]);
  }
  if (t < 81) {
    int dr = t / 9 - 4, dc = t % 9 - 4;
    int j = (((r + dr) & 31) << 5) | ((c + dc) & 31);
    float s = 0.f;
    int erlo = dr - 2 < -2 ? -2 : dr - 2, erhi = dr + 2 > 2 ? 2 : dr + 2;
    int eclo = dc - 2 < -2 ? -2 : dc - 2, echi = dc + 2 > 2 ? 2 : dc + 2;
    for (int er = erlo; er <= erhi; ++er)
      for (int ec = eclo; ec <= echi; ++ec) {
        int m = (((r + er) & 31) << 5) | ((c + ec) & 31);
        s += Wl[i * 1024 + m] * Wq[m * 1024 + j];
      }
    Wqkv[i * 1024 + j] = f2bf(s);
  }
  if (t == 96) {
    float s = 0.f;
    for (int e = 0; e < 25; ++e) {
      int dr = e / 5 - 2, dc = e % 5 - 2;
      int m = (((r + dr) & 31) << 5) | ((c + dc) & 31);
      s += Wl[i * 1024 + m] * bq[m];
    }
    biasAll[i] = s;
  }
  if (t == 97) biasAll[1024 + i] = bk[i];
  if (t == 98) biasAll[2048 + i] = bv[i];
}

// ---------------------------------------------------------------------------
// 256x256-tile, BK=64, 8-wave (2Mx4N) GEMM, m201 cadence (8 phases / 2
// K-tiles, one half-tile staged per slot, counted vmcnt(4)/(6), never 0
// mid-loop; NO global stores inside the K-loop — they poison the counted
// vmcnt ledger, measured +29 us in r6), XOR swizzle (g ^ (row&7)) on
// stage-source and ds_read, bijective XCD-aware block swizzle (flat grid).
// OUTMODE 0: QKV. bn<8: bf16 q/k out + bias; bn>=8: bias-added V written
//   transposed to vT[b][h][s] via LDS tile (fused transpose).
// OUTMODE 2: e=exp(acc*scale) bf16 out + row partials -> Lpart[row*8+bn]
// OUTMODE 3: fp32 out * invL[row] (deferred softmax normalization)
// ---------------------------------------------------------------------------
template <int OUTMODE>
__global__ __launch_bounds__(512, 2) void gemm256(
    const unsigned short* __restrict__ A, const unsigned short* __restrict__ B,
    void* __restrict__ Cv, const float* __restrict__ auxc, float* __restrict__ auxw,
    int lda, int ldb, int ldc, int K, float scale,
    size_t sA, size_t sB, size_t sC, int nx, int ny) {
  // K-loop staging: bytes [0,131072). OUTMODE 0 v-epilogue reuses as
  // [256][264] ushort tile (132 KiB).
  __shared__ __align__(16) unsigned short lds[67584];
  const int t = threadIdx.x;
  const int lane = t & 63;
  const int wv = t >> 6;          // 0..7
  const int wm = wv >> 2;         // 0..1  (row half)
  const int wn = wv & 3;          // 0..3  (col quarter)
  const int l15 = lane & 15, lq = lane >> 4;

  // --- XCD-aware bijective swizzle (nwg % 8 == 0 guaranteed by launches) ---
  const int nwg = gridDim.x;
  const int hid = blockIdx.x;
  const int logical = (hid & 7) * (nwg >> 3) + (hid >> 3);
  const int bn = logical % nx;
  const int bm = (logical / nx) % ny;
  const int bz = logical / (nx * ny);

  A += sA * bz; B += sB * bz;

  const int srow = t >> 3;               // staging row within half 0..63
  const int sg = (t & 7) ^ (srow & 7);   // pre-swizzled 16B-group in source

  // Stage one half-tile (128 rows x 64 cols): 2 gload_lds x 512 thr x 16B.
#define STG_A(h, tile_) do {                                                     \
    gload_lds16(A + (size_t)(bm * 256 + (h) * 128 + srow) * lda + (tile_) * 64 + sg * 8, \
                &lds[(((tile_) & 1) << 14) + (h) * 8192 + wv * 512]);            \
    gload_lds16(A + (size_t)(bm * 256 + (h) * 128 + 64 + srow) * lda + (tile_) * 64 + sg * 8, \
                &lds[(((tile_) & 1) << 14) + (h) * 8192 + 4096 + wv * 512]);     \
  } while (0)
#define STG_B(h, tile_) do {                                                     \
    gload_lds16(B + (size_t)(bn * 256 + (h) * 128 + srow) * ldb + (tile_) * 64 + sg * 8, \
                &lds[32768 + (((tile_) & 1) << 14) + (h) * 8192 + wv * 512]);    \
    gload_lds16(B + (size_t)(bn * 256 + (h) * 128 + 64 + srow) * ldb + (tile_) * 64 + sg * 8, \
                &lds[32768 + (((tile_) & 1) << 14) + (h) * 8192 + 4096 + wv * 512]); \
  } while (0)

#define LOADA(arr, ro)                                                           \
  _Pragma("unroll") for (int i = 0; i < 4; ++i) {                                \
    int rA = wm * 128 + (ro) + i * 16 + l15;                                     \
    _Pragma("unroll") for (int ks = 0; ks < 2; ++ks)                             \
      arr[i][ks] = *(const short8*)&lds[bo_ + rA * 64 + (((ks * 4 + lq) ^ (rA & 7)) << 3)]; \
  }
#define LOADB(arr, ro)                                                           \
  _Pragma("unroll") for (int j = 0; j < 2; ++j) {                                \
    int rB = wn * 64 + (ro) + j * 16 + l15;                                      \
    _Pragma("unroll") for (int ks = 0; ks < 2; ++ks)                             \
      arr[j][ks] = *(const short8*)&lds[32768 + bo_ + rB * 64 + (((ks * 4 + lq) ^ (rB & 7)) << 3)]; \
  }
#define MFMA8(mb, nb, aa, bb)                                                    \
  _Pragma("unroll") for (int i = 0; i < 4; ++i)                                  \
    _Pragma("unroll") for (int j = 0; j < 2; ++j) {                              \
      acc[(mb) + i][(nb) + j] = __builtin_amdgcn_mfma_f32_16x16x32_bf16(         \
          aa[i][0], bb[j][0], acc[(mb) + i][(nb) + j], 0, 0, 0);                 \
      acc[(mb) + i][(nb) + j] = __builtin_amdgcn_mfma_f32_16x16x32_bf16(         \
          aa[i][1], bb[j][1], acc[(mb) + i][(nb) + j], 0, 0, 0);                 \
    }
#define FENCE asm volatile("" ::: "memory")
#define BAR __builtin_amdgcn_s_barrier()
#define SP1 __builtin_amdgcn_s_setprio(1)
#define SP0 __builtin_amdgcn_s_setprio(0)

  floatx4 acc[8][4];
#pragma unroll
  for (int i = 0; i < 8; ++i)
#pragma unroll
    for (int j = 0; j < 4; ++j) acc[i][j] = (floatx4){0.f, 0.f, 0.f, 0.f};

  const int NT = K >> 6;  // even, >= 2 (16 or 32 here)

  // Prologue: tile0 fully (8 loads) + B0,A0,B1 of tile1 (6 loads);
  // vmcnt(6) -> tile0 resident, 3 half-tiles of tile1 in flight.
  STG_A(0, 0); STG_A(1, 0); STG_B(0, 0); STG_B(1, 0);
  FENCE;
  STG_B(0, 1); STG_A(0, 1); STG_B(1, 1);
  asm volatile("s_waitcnt vmcnt(6)" ::: "memory");
  BAR;

  for (int T = 0; T < NT; T += 2) {
    short8 aF[4][2], bFa[2][2], bFb[2][2];
    // ================= tile T (buffer 0) =================
    {
      const int bo_ = 0;
      // ph1: Q(0,0)
      LOADA(aF, 0); LOADB(bFa, 0);
      STG_A(1, T + 1);
      FENCE; BAR;
      SP1; MFMA8(0, 0, aF, bFa); SP0;
      FENCE; BAR;
      // ph2: Q(0,1)
      LOADB(bFb, 32);
      FENCE; BAR;
      SP1; MFMA8(0, 2, aF, bFb); SP0;
      FENCE; BAR;
      // ph3: Q(1,1)  (reuse aF regs for upper A half)
      LOADA(aF, 64);
      if (T + 2 < NT) STG_B(0, T + 2);
      FENCE; BAR;
      SP1; MFMA8(4, 2, aF, bFb); SP0;
      FENCE; BAR;
      // ph4: Q(1,0)
      if (T + 2 < NT) STG_A(0, T + 2);
      FENCE; BAR;
      SP1; MFMA8(4, 0, aF, bFa); SP0;
      if (T + 2 < NT) { asm volatile("s_waitcnt vmcnt(4)" ::: "memory"); }
      else            { asm volatile("s_waitcnt vmcnt(0)" ::: "memory"); }
      FENCE; BAR;
    }
    // ================= tile T+1 (buffer 1) =================
    {
      const int bo_ = 1 << 14;
      // ph5: Q(0,0)
      LOADA(aF, 0); LOADB(bFa, 0);
      if (T + 2 < NT) { STG_B(1, T + 2); STG_A(1, T + 2); }
      FENCE; BAR;
      SP1; MFMA8(0, 0, aF, bFa); SP0;
      FENCE; BAR;
      // ph6: Q(0,1)
      LOADB(bFb, 32);
      FENCE; BAR;
      SP1; MFMA8(0, 2, aF, bFb); SP0;
      FENCE; BAR;
      // ph7: Q(1,1)
      LOADA(aF, 64);
      if (T + 3 < NT) STG_B(0, T + 3);
      FENCE; BAR;
      SP1; MFMA8(4, 2, aF, bFb); SP0;
      FENCE; BAR;
      // ph8: Q(1,0)
      if (T + 3 < NT) { STG_A(0, T + 3); STG_B(1, T + 3); }
      FENCE; BAR;
      SP1; MFMA8(4, 0, aF, bFa); SP0;
      if (T + 3 < NT) { asm volatile("s_waitcnt vmcnt(6)" ::: "memory"); }
      else            { asm volatile("s_waitcnt vmcnt(0)" ::: "memory"); }
      FENCE; BAR;
    }
  }
#undef STG_A
#undef STG_B
#undef LOADA
#undef LOADB
#undef MFMA8

  // acc[m][n]: row = row0 + (m>>2)*64 + (m&3)*16 + lq*4 + r2
  //            col = col0 + (n>>1)*32 + (n&1)*16 + l15
  const int row0 = bm * 256 + wm * 128;
  const int col0 = bn * 256 + wn * 64;

  if (OUTMODE == 0) {
    if (bn < 8) {
      // q/k blocks: normal bf16 write + bias
      unsigned short* C = (unsigned short*)Cv;
#pragma unroll
      for (int m = 0; m < 8; ++m) {
        int rb = row0 + ((m >> 2) << 6) + ((m & 3) << 4) + (lq << 2);
#pragma unroll
        for (int n = 0; n < 4; ++n) {
          int col = col0 + ((n >> 1) << 5) + ((n & 1) << 4) + l15;
          float bb = auxc[col];
#pragma unroll
          for (int r2 = 0; r2 < 4; ++r2)
            C[(size_t)(rb + r2) * ldc + col] = f2bf(acc[m][n][r2] + bb);
        }
      }
    } else {
      // v blocks: bias + transpose via LDS -> vT[b][h][s] (fused transpose_v)
      unsigned short (*lds2)[264] = (unsigned short (*)[264])lds;
#pragma unroll
      for (int m = 0; m < 8; ++m) {
        int sr = wm * 128 + ((m >> 2) << 6) + ((m & 3) << 4) + (lq << 2);
#pragma unroll
        for (int n = 0; n < 4; ++n) {
          int colg = col0 + ((n >> 1) << 5) + ((n & 1) << 4) + l15;  // 2048..3071
          int h = (colg - 2048) & 255;  // local h within this block's 256 cols
          float bb = auxc[colg];
          ushort4 pk;
          pk.x = f2bf(acc[m][n][0] + bb);
          pk.y = f2bf(acc[m][n][1] + bb);
          pk.z = f2bf(acc[m][n][2] + bb);
          pk.w = f2bf(acc[m][n][3] + bb);
          *(ushort4*)&lds2[h][sr] = pk;  // 8B write, s-contiguous
        }
      }
      __syncthreads();
      unsigned short* vTp = (unsigned short*)auxw;
      const int b = bm >> 3;
      const int s0 = (bm & 7) * 256;
      const int h0 = (bn - 8) * 256;
      const int hh = t >> 1, sh = (t & 1) * 128;
      unsigned short* dst = vTp + ((size_t)b * 1024 + h0 + hh) * 2048 + s0 + sh;
      const unsigned short* src = &lds2[hh][sh];
#pragma unroll
      for (int k2 = 0; k2 < 16; ++k2)
        *(short8*)&dst[k2 * 8] = *(const short8*)&src[k2 * 8];
    }
  } else if (OUTMODE == 2) {
    unsigned short* C = (unsigned short*)Cv + sC * bz;
    float p[8][4];
#pragma unroll
    for (int m = 0; m < 8; ++m)
#pragma unroll
      for (int r2 = 0; r2 < 4; ++r2) p[m][r2] = 0.f;
#pragma unroll
    for (int m = 0; m < 8; ++m) {
      int rb = row0 + ((m >> 2) << 6) + ((m & 3) << 4) + (lq << 2);
#pragma unroll
      for (int n = 0; n < 4; ++n) {
        int col = col0 + ((n >> 1) << 5) + ((n & 1) << 4) + l15;
#pragma unroll
        for (int r2 = 0; r2 < 4; ++r2) {
          float e = __expf(acc[m][n][r2] * scale);
          C[(size_t)(rb + r2) * ldc + col] = f2bf(e);
          p[m][r2] += e;
        }
      }
    }
    // reduce over the 16 lanes (l15) sharing each row
#pragma unroll
    for (int m = 0; m < 8; ++m)
#pragma unroll
      for (int r2 = 0; r2 < 4; ++r2) {
        float v = p[m][r2];
        v += __shfl_xor(v, 1); v += __shfl_xor(v, 2);
        v += __shfl_xor(v, 4); v += __shfl_xor(v, 8);
        p[m][r2] = v;
      }
    float* sred = (float*)lds;  // [4 wn][256 rows]; all LDS traffic drained
    if (l15 == 0) {
#pragma unroll
      for (int m = 0; m < 8; ++m)
#pragma unroll
        for (int r2 = 0; r2 < 4; ++r2)
          sred[wn * 256 + wm * 128 + ((m >> 2) << 6) + ((m & 3) << 4) + (lq << 2) + r2] = p[m][r2];
    }
    __syncthreads();
    if (t < 256) {
      float L = sred[t] + sred[256 + t] + sred[512 + t] + sred[768 + t];
      auxw[((size_t)bz * 2048 + bm * 256 + t) * 8 + bn] = L;
    }
  } else {  // OUTMODE 3: out = acc * invL[row] (invL from global)
    float* C = (float*)Cv + sC * bz;
#pragma unroll
    for (int m = 0; m < 8; ++m) {
      int rb = row0 + ((m >> 2) << 6) + ((m & 3) << 4) + (lq << 2);
      float il[4];
#pragma unroll
      for (int r2 = 0; r2 < 4; ++r2)
        il[r2] = auxc[(size_t)bz * 2048 + rb + r2];
#pragma unroll
      for (int n = 0; n < 4; ++n) {
        int col = col0 + ((n >> 1) << 5) + ((n & 1) << 4) + l15;
#pragma unroll
        for (int r2 = 0; r2 < 4; ++r2)
          C[(size_t)(rb + r2) * ldc + col] = acc[m][n][r2] * il[r2];
      }
    }
  }
}

// ---------------------------------------------------------------------------
// Finish softmax: per row, L = sum of 8 partials; invL = 1/L; write probs
// fp32 = e(bf16) * invL.  One block (256 thr) per row.
// ---------------------------------------------------------------------------
__global__ __launch_bounds__(256) void finish_softmax(
    const float* __restrict__ Lpart, const unsigned short* __restrict__ pb,
    float* __restrict__ invL, float* __restrict__ probs) {
  const size_t row = blockIdx.x;
  const int t = threadIdx.x;
  __shared__ float sInv;
  if (t < 64) {
    float s = (t < 8) ? Lpart[row * 8 + t] : 0.f;
    s += __shfl_xor(s, 1); s += __shfl_xor(s, 2); s += __shfl_xor(s, 4);
    if (t == 0) {
      float inv = 1.0f / s;
      sInv = inv;
      invL[row] = inv;
    }
  }
  __syncthreads();
  float inv = sInv;
  const ushort4* pv = (const ushort4*)(pb + row * 2048);
  float4* pr = (float4*)(probs + row * 2048);
  ushort4 a = pv[t * 2], b = pv[t * 2 + 1];
  float4 o0, o1;
  o0.x = bf2f(a.x) * inv; o0.y = bf2f(a.y) * inv;
  o0.z = bf2f(a.z) * inv; o0.w = bf2f(a.w) * inv;
  o1.x = bf2f(b.x) * inv; o1.y = bf2f(b.y) * inv;
  o1.z = bf2f(b.z) * inv; o1.w = bf2f(b.w) * inv;
  pr[t * 2] = o0; pr[t * 2 + 1] = o1;
}

// ---------------------------------------------------------------------------
extern "C" void kernel_launch(void* const* d_in, const int* in_sizes, int n_in,
                              void* d_out, int out_size, void* d_ws, size_t ws_size,
                              hipStream_t stream) {
  const float* x  = (const float*)d_in[0];
  const float* Wq = (const float*)d_in[1];
  const float* bq = (const float*)d_in[2];
  const float* Wk = (const float*)d_in[3];
  const float* bk = (const float*)d_in[4];
  const float* Wv = (const float*)d_in[5];
  const float* bv = (const float*)d_in[6];
  const float* Wl = (const float*)d_in[7];

  const int B = 8, S = 2048, H = 1024;
  float* out   = (float*)d_out;                     // [B,S,H]
  float* probs = (float*)d_out + (size_t)B * S * H; // [B,S,S]

  char* ws = (char*)d_ws;
  unsigned short* qkv  = (unsigned short*)(ws + 0);           // 100.7MB [16384][3072] (v third unused)
  unsigned short* pb   = (unsigned short*)(ws + 100663296);   // 67MB [B*S][2048] e=exp(s)
  unsigned short* xb   = (unsigned short*)(ws + 167772160);   // 33.5MB
  unsigned short* Wqkv = (unsigned short*)(ws + 201326592);   // 6.3MB [3072][1024]
  float* biasAll       = (float*)(ws + 207618048);            // 12KB
  float* Lpart         = (float*)(ws + 207630336);            // 512KB [16384][8]
  float* invL          = (float*)(ws + 208678912);            // 64KB [16384]
  unsigned short* vT   = (unsigned short*)(ws + 209715200);   // 33.5MB [B][H][S]

  prep_cast<<<17408, 128, 0, stream>>>(Wq, Wk, Wv, Wl, bq, bk, bv, Wqkv, biasAll,
                                       (const float4*)x, (ushort4*)xb);

  // qkv(q,k) = x @ Wqkv^T + biasAll; v written transposed to vT (fused)
  gemm256<0><<<768, 512, 0, stream>>>(xb, Wqkv, qkv, biasAll, (float*)vT,
      H, H, 3 * H, H, 1.f, 0, 0, 0, 12, 64);

  // e = exp(q@k^T/32) bf16 -> pb, row-block partial sums -> Lpart (8*8*8)
  gemm256<2><<<512, 512, 0, stream>>>(qkv, qkv + 1024, pb, nullptr, Lpart,
      3 * H, 3 * H, S, H, 1.0f / 32.0f, (size_t)S * 3 * H, (size_t)S * 3 * H, (size_t)S * S, 8, 8);

  finish_softmax<<<16384, 256, 0, stream>>>(Lpart, pb, invL, probs);

  // out = (e @ v) * invL[row]   (4*8*8)
  gemm256<3><<<256, 512, 0, stream>>>(pb, vT, out, invL, nullptr,
      S, S, H, S, 1.0f, (size_t)S * S, (size_t)H * S, (size_t)S * H, 4, 8);
}